// Round 1
// baseline (10187.798 us; speedup 1.0000x reference)
//
#include <hip/hip_runtime.h>

#define T_FULL 1024
#define NBATCH 64
#define IDIM   512
#define NCH    256
#define GD     768
#define ODIM   3
#define NBLK   16

typedef _Float16 half8   __attribute__((ext_vector_type(8)));
typedef float    floatx4 __attribute__((ext_vector_type(4)));

__device__ __forceinline__ float sigmoidf_(float x) { return 1.0f / (1.0f + __expf(-x)); }
// NaN-safe tanh for large |x|
__device__ __forceinline__ float tanhf_(float x)    { return 1.0f - 2.0f / (__expf(2.0f * x) + 1.0f); }

__device__ __forceinline__ floatx4 splat4(float v) { floatx4 r; r[0]=v; r[1]=v; r[2]=v; r[3]=v; return r; }

__device__ __forceinline__ half8 cvt8(const float* __restrict__ p) {
  floatx4 a = *(const floatx4*)p;
  floatx4 b = *(const floatx4*)(p + 4);
  half8 h;
  h[0]=(_Float16)a[0]; h[1]=(_Float16)a[1]; h[2]=(_Float16)a[2]; h[3]=(_Float16)a[3];
  h[4]=(_Float16)b[0]; h[5]=(_Float16)b[1]; h[6]=(_Float16)b[2]; h[7]=(_Float16)b[3];
  return h;
}

// ---------------------------------------------------------------------------
// Precompute GEMM: Xw[m][g] = sum_{k<512} x[b][t0+t][k] * w_ih0[g][k]
// m = t_local*64 + b, f16 output, fp32 accum. 128x128 tile, BK=32, 4 waves.
// ---------------------------------------------------------------------------
__global__ __launch_bounds__(256)
void xw_gemm(const float* __restrict__ x, const float* __restrict__ w_ih0,
             _Float16* __restrict__ Xw, int t0, int Tc) {
  __shared__ _Float16 As[128 * 32];
  __shared__ _Float16 Bs[128 * 32];
  const int tid  = threadIdx.x;
  const int lane = tid & 63;
  const int wave = tid >> 6;
  const int lq = lane >> 4, lc = lane & 15;
  const int wm = wave >> 1, wn = wave & 1;

  // staging: thread covers row sr, 16 elems starting at sh
  const int sr = tid >> 1;
  const int sh = (tid & 1) * 16;
  const int m  = blockIdx.x * 128 + sr;
  const float* arow = x + ((size_t)(m & 63) * T_FULL + (size_t)(t0 + (m >> 6))) * IDIM;
  const float* brow = w_ih0 + (size_t)(blockIdx.y * 128 + sr) * GD;

  floatx4 acc[4][4];
  #pragma unroll
  for (int i = 0; i < 4; ++i)
    #pragma unroll
    for (int j = 0; j < 4; ++j) acc[i][j] = splat4(0.f);

  for (int kk = 0; kk < IDIM; kk += 32) {
    __syncthreads();
    #pragma unroll
    for (int kb = 0; kb < 2; ++kb) {
      const int k0  = sh + kb * 8;
      const int gis = (k0 >> 3) ^ ((sr >> 2) & 3);   // XOR swizzle (in 8-elem groups)
      *(half8*)((char*)As + sr * 64 + gis * 16) = cvt8(arow + kk + k0);
      *(half8*)((char*)Bs + sr * 64 + gis * 16) = cvt8(brow + kk + k0);
    }
    __syncthreads();
    half8 af[4], bf[4];
    #pragma unroll
    for (int ms = 0; ms < 4; ++ms) {
      const int r = wm * 64 + ms * 16 + lc;
      af[ms] = *(const half8*)((char*)As + r * 64 + ((lq ^ ((r >> 2) & 3)) * 16));
    }
    #pragma unroll
    for (int ns = 0; ns < 4; ++ns) {
      const int r = wn * 64 + ns * 16 + lc;
      bf[ns] = *(const half8*)((char*)Bs + r * 64 + ((lq ^ ((r >> 2) & 3)) * 16));
    }
    #pragma unroll
    for (int ms = 0; ms < 4; ++ms)
      #pragma unroll
      for (int ns = 0; ns < 4; ++ns)
        acc[ms][ns] = __builtin_amdgcn_mfma_f32_16x16x32_f16(af[ms], bf[ns], acc[ms][ns], 0, 0, 0);
  }

  #pragma unroll
  for (int ms = 0; ms < 4; ++ms)
    #pragma unroll
    for (int ns = 0; ns < 4; ++ns)
      #pragma unroll
      for (int q = 0; q < 4; ++q) {
        const int mloc = blockIdx.x * 128 + wm * 64 + ms * 16 + lq * 4 + q;
        const int g    = blockIdx.y * 128 + wn * 64 + ns * 16 + lc;
        Xw[(size_t)mloc * GD + g] = (_Float16)acc[ms][ns][q];
      }
}

// ---------------------------------------------------------------------------
// Hand-rolled 16-block grid barrier (device-scope flags + fences).
// ---------------------------------------------------------------------------
__device__ __forceinline__ void grid_barrier(unsigned int* flags, int blk, unsigned int ep) {
  __syncthreads();                      // drains all waves' stores (vmcnt0 before s_barrier)
  if (threadIdx.x == 0) {
    __builtin_amdgcn_fence(__ATOMIC_RELEASE, "agent");
    __hip_atomic_store(&flags[blk * 32], ep, __ATOMIC_RELAXED, __HIP_MEMORY_SCOPE_AGENT);
  }
  if (threadIdx.x < 64) {
    const int lane = threadIdx.x;
    const int idx  = (lane < NBLK) ? lane * 32 : 0;
    int spins = 0;
    for (;;) {
      unsigned int v = __hip_atomic_load(&flags[idx], __ATOMIC_RELAXED, __HIP_MEMORY_SCOPE_AGENT);
      if (lane >= NBLK) v = ep;
      if (__all((int)(v >= ep))) break;
      if (++spins > (1 << 16)) break;   // safety: never hang forever
      __builtin_amdgcn_s_sleep(1);
    }
    __builtin_amdgcn_fence(__ATOMIC_ACQUIRE, "agent");
  }
  __syncthreads();
}

// ---------------------------------------------------------------------------
// Persistent recurrent kernel: 16 blocks x 256 threads. Block owns 16 channels,
// wave owns 16 batches. All weights live in registers as f16 MFMA fragments.
// Per step: phase1 (gh0, gh1, v, layer0 combine, publish h0), barrier,
//           phase2 (gi1, layer1 combine, publish h1), barrier.
// ---------------------------------------------------------------------------
__global__ __launch_bounds__(256, 1)
void rec_step(const float* __restrict__ w_ih0, const float* __restrict__ w_hh0,
              const float* __restrict__ w_ih1, const float* __restrict__ w_hh1,
              const float* __restrict__ b_ih0, const float* __restrict__ b_hh0,
              const float* __restrict__ b_ih1, const float* __restrict__ b_hh1,
              const float* __restrict__ embed_w, const float* __restrict__ embed_b,
              const float* __restrict__ proj_w, const float* __restrict__ proj_b,
              const _Float16* __restrict__ Xw, float* __restrict__ out,
              _Float16* h0_pub, _Float16* h1_pub, unsigned int* flags,
              int t0, int Tc, int lastChunk) {
  const int tid  = threadIdx.x;
  const int wave = tid >> 6;
  const int lane = tid & 63;
  const int lq = lane >> 4, lc = lane & 15;
  const int blk = blockIdx.x;
  const int c   = blk * 16 + lc;               // this thread's channel

  // ---- load weight fragments (fp32 -> f16), held in registers for all steps
  half8 Whh0[3][8], Whh1[3][8], Wih1[3][8], Pj[8];
  #pragma unroll
  for (int g = 0; g < 3; ++g) {
    const int row = g * NCH + c;
    #pragma unroll
    for (int ks = 0; ks < 8; ++ks) {
      const int k0 = ks * 32 + lq * 8;
      Whh0[g][ks] = cvt8(w_hh0 + (size_t)row * NCH + k0);
      Whh1[g][ks] = cvt8(w_hh1 + (size_t)row * NCH + k0);
      Wih1[g][ks] = cvt8(w_ih1 + (size_t)row * NCH + k0);
    }
  }
  #pragma unroll
  for (int ks = 0; ks < 8; ++ks) {
    const int k0 = ks * 32 + lq * 8;
    half8 z;
    #pragma unroll
    for (int j = 0; j < 8; ++j) z[j] = (_Float16)0.f;
    Pj[ks] = (lc < 3) ? cvt8(proj_w + lc * NCH + k0) : z;
  }

  // ---- folded constants: Wce = W_ih0[:,512:] @ embed_w ; bi0 += W_ih0[:,512:] @ embed_b
  float Wce[3][3], bi0[3], bh0v[3], bi1v[3], bh1v[3];
  #pragma unroll
  for (int g = 0; g < 3; ++g) {
    const int row = g * NCH + c;
    float a0 = 0.f, a1 = 0.f, a2 = 0.f, ab = b_ih0[row];
    const float* wr = w_ih0 + (size_t)row * GD + IDIM;
    for (int k = 0; k < NCH; ++k) {
      const float w = wr[k];
      a0 += w * embed_w[k * 3 + 0];
      a1 += w * embed_w[k * 3 + 1];
      a2 += w * embed_w[k * 3 + 2];
      ab += w * embed_b[k];
    }
    Wce[g][0] = a0; Wce[g][1] = a1; Wce[g][2] = a2;
    bi0[g] = ab;
    bh0v[g] = b_hh0[row]; bi1v[g] = b_ih1[row]; bh1v[g] = b_hh1[row];
  }
  const float pb = (lc < 3) ? proj_b[lc] : 0.f;

  // ---- per-thread fp32 state (channel c, 4 batches)
  float h0st[4] = {0.f, 0.f, 0.f, 0.f};
  float h1st[4] = {0.f, 0.f, 0.f, 0.f};
  if (t0 > 0) {  // resume from previous chunk's published state
    const int rp0 = ((t0 & 1) ^ 1) * (NBATCH * NCH);
    #pragma unroll
    for (int q = 0; q < 4; ++q) {
      const int b = wave * 16 + lq * 4 + q;
      h0st[q] = (float)h0_pub[rp0 + b * NCH + c];
      h1st[q] = (float)h1_pub[rp0 + b * NCH + c];
    }
  }
  floatx4 ag1[3];
  const int arow = (wave * 16 + lc) * NCH;     // A-fragment row base

  for (int lt = 0; lt < Tc; ++lt) {
    const int gt = t0 + lt;
    const int rp = ((gt & 1) ^ 1) * (NBATCH * NCH);
    const int wp = (gt & 1) * (NBATCH * NCH);
    const _Float16* h0r = h0_pub + rp;
    const _Float16* h1r = h1_pub + rp;

    // ======== PHASE 1 ========
    // gh0 = h0(t-1) @ Whh0^T + b_hh0
    floatx4 ah0[3];
    #pragma unroll
    for (int g = 0; g < 3; ++g) ah0[g] = splat4(bh0v[g]);
    #pragma unroll
    for (int hh = 0; hh < 2; ++hh) {
      half8 ha[4];
      #pragma unroll
      for (int i = 0; i < 4; ++i) ha[i] = *(const half8*)(h0r + arow + (hh * 4 + i) * 32 + lq * 8);
      #pragma unroll
      for (int g = 0; g < 3; ++g)
        #pragma unroll
        for (int i = 0; i < 4; ++i)
          ah0[g] = __builtin_amdgcn_mfma_f32_16x16x32_f16(ha[i], Whh0[g][hh * 4 + i], ah0[g], 0, 0, 0);
    }
    // gh1 = h1(t-1) @ Whh1^T + b_hh1 ; v-pre = h1(t-1) @ proj^T + proj_b
    #pragma unroll
    for (int g = 0; g < 3; ++g) ag1[g] = splat4(bh1v[g]);
    floatx4 av = splat4(pb);
    #pragma unroll
    for (int hh = 0; hh < 2; ++hh) {
      half8 ha[4];
      #pragma unroll
      for (int i = 0; i < 4; ++i) ha[i] = *(const half8*)(h1r + arow + (hh * 4 + i) * 32 + lq * 8);
      #pragma unroll
      for (int g = 0; g < 3; ++g)
        #pragma unroll
        for (int i = 0; i < 4; ++i)
          ag1[g] = __builtin_amdgcn_mfma_f32_16x16x32_f16(ha[i], Whh1[g][hh * 4 + i], ag1[g], 0, 0, 0);
      #pragma unroll
      for (int i = 0; i < 4; ++i)
        av = __builtin_amdgcn_mfma_f32_16x16x32_f16(ha[i], Pj[hh * 4 + i], av, 0, 0, 0);
    }
    // v(t-1) = sigmoid(v-pre); redistribute to all lanes; write output row t-1
    float vv0[4], vv1[4], vv2[4];
    if (gt == 0) {
      #pragma unroll
      for (int q = 0; q < 4; ++q) { vv0[q] = 0.f; vv1[q] = 0.f; vv2[q] = 0.f; }
    } else {
      float sv[4];
      #pragma unroll
      for (int q = 0; q < 4; ++q) sv[q] = (lc < 3) ? sigmoidf_(av[q]) : 0.f;
      if (blk == 0 && lc < 3) {
        #pragma unroll
        for (int q = 0; q < 4; ++q)
          out[((size_t)(wave * 16 + lq * 4 + q) * T_FULL + (gt - 1)) * ODIM + lc] = sv[q];
      }
      #pragma unroll
      for (int q = 0; q < 4; ++q) {
        vv0[q] = __shfl(sv[q], (lq << 4) + 0, 64);
        vv1[q] = __shfl(sv[q], (lq << 4) + 1, 64);
        vv2[q] = __shfl(sv[q], (lq << 4) + 2, 64);
      }
    }
    // gi0 = Xw[t] + v @ Wce^T + bi0 ; GRU layer-0 combine
    const _Float16* xwp = Xw + (size_t)lt * (NBATCH * GD);
    float h0n[4];
    #pragma unroll
    for (int q = 0; q < 4; ++q) {
      const int b = wave * 16 + lq * 4 + q;
      const float i_r = (float)xwp[b * GD + 0 * NCH + c] + bi0[0] + vv0[q] * Wce[0][0] + vv1[q] * Wce[0][1] + vv2[q] * Wce[0][2];
      const float i_z = (float)xwp[b * GD + 1 * NCH + c] + bi0[1] + vv0[q] * Wce[1][0] + vv1[q] * Wce[1][1] + vv2[q] * Wce[1][2];
      const float i_n = (float)xwp[b * GD + 2 * NCH + c] + bi0[2] + vv0[q] * Wce[2][0] + vv1[q] * Wce[2][1] + vv2[q] * Wce[2][2];
      const float r = sigmoidf_(i_r + ah0[0][q]);
      const float z = sigmoidf_(i_z + ah0[1][q]);
      const float n = tanhf_(i_n + r * ah0[2][q]);
      h0n[q] = (1.f - z) * n + z * h0st[q];
      h0st[q] = h0n[q];
    }
    {
      _Float16* h0w = h0_pub + wp;
      #pragma unroll
      for (int q = 0; q < 4; ++q)
        h0w[(wave * 16 + lq * 4 + q) * NCH + c] = (_Float16)h0n[q];
    }
    grid_barrier(flags, blk, (unsigned)(2 * gt + 1));

    // ======== PHASE 2 ========
    const _Float16* h0r2 = h0_pub + wp;
    floatx4 ai1[3];
    #pragma unroll
    for (int g = 0; g < 3; ++g) ai1[g] = splat4(bi1v[g]);
    #pragma unroll
    for (int hh = 0; hh < 2; ++hh) {
      half8 ha[4];
      #pragma unroll
      for (int i = 0; i < 4; ++i) ha[i] = *(const half8*)(h0r2 + arow + (hh * 4 + i) * 32 + lq * 8);
      #pragma unroll
      for (int g = 0; g < 3; ++g)
        #pragma unroll
        for (int i = 0; i < 4; ++i)
          ai1[g] = __builtin_amdgcn_mfma_f32_16x16x32_f16(ha[i], Wih1[g][hh * 4 + i], ai1[g], 0, 0, 0);
    }
    float h1n[4];
    #pragma unroll
    for (int q = 0; q < 4; ++q) {
      const float r = sigmoidf_(ai1[0][q] + ag1[0][q]);
      const float z = sigmoidf_(ai1[1][q] + ag1[1][q]);
      const float n = tanhf_(ai1[2][q] + r * ag1[2][q]);
      h1n[q] = (1.f - z) * n + z * h1st[q];
      h1st[q] = h1n[q];
    }
    {
      _Float16* h1w = h1_pub + wp;
      #pragma unroll
      for (int q = 0; q < 4; ++q)
        h1w[(wave * 16 + lq * 4 + q) * NCH + c] = (_Float16)h1n[q];
    }
    grid_barrier(flags, blk, (unsigned)(2 * gt + 2));
  }

  // tail: final v(T-1) from last published h1
  if (lastChunk && blk == 0) {
    const _Float16* h1r = h1_pub + (((t0 + Tc - 1) & 1)) * (NBATCH * NCH);
    floatx4 av = splat4(pb);
    #pragma unroll
    for (int ks = 0; ks < 8; ++ks) {
      half8 ha = *(const half8*)(h1r + arow + ks * 32 + lq * 8);
      av = __builtin_amdgcn_mfma_f32_16x16x32_f16(ha, Pj[ks], av, 0, 0, 0);
    }
    if (lc < 3) {
      #pragma unroll
      for (int q = 0; q < 4; ++q)
        out[((size_t)(wave * 16 + lq * 4 + q) * T_FULL + (T_FULL - 1)) * ODIM + lc] = sigmoidf_(av[q]);
    }
  }
}

extern "C" void kernel_launch(void* const* d_in, const int* in_sizes, int n_in,
                              void* d_out, int out_size, void* d_ws, size_t ws_size,
                              hipStream_t stream) {
  const float* x       = (const float*)d_in[0];
  const float* embed_w = (const float*)d_in[1];
  const float* embed_b = (const float*)d_in[2];
  const float* w_ih0   = (const float*)d_in[3];
  const float* w_hh0   = (const float*)d_in[4];
  const float* b_ih0   = (const float*)d_in[5];
  const float* b_hh0   = (const float*)d_in[6];
  const float* w_ih1   = (const float*)d_in[7];
  const float* w_hh1   = (const float*)d_in[8];
  const float* b_ih1   = (const float*)d_in[9];
  const float* b_hh1   = (const float*)d_in[10];
  const float* proj_w  = (const float*)d_in[11];
  const float* proj_b  = (const float*)d_in[12];
  float* out = (float*)d_out;

  char* ws = (char*)d_ws;
  _Float16* h0_pub = (_Float16*)(ws);                 // 2 parity buffers, 64KB
  _Float16* h1_pub = (_Float16*)(ws + 65536);         // 64KB
  unsigned int* flags = (unsigned int*)(ws + 131072); // 2KB used
  _Float16* Xw = (_Float16*)(ws + 262144);

  const size_t per_t = (size_t)NBATCH * GD * sizeof(_Float16);  // 98304 B
  size_t xw_avail = (ws_size > 262144) ? (ws_size - 262144) : 0;
  long maxTc = (long)(xw_avail / per_t);
  int Tc = 2;
  while ((long)Tc * 2 <= maxTc && Tc * 2 <= T_FULL) Tc *= 2;

  // zero state + flags every call (graph replay safe)
  hipMemsetAsync(ws, 0, 262144, stream);

  for (int t0 = 0; t0 < T_FULL; t0 += Tc) {
    dim3 g1(Tc * NBATCH / 128, GD / 128);
    xw_gemm<<<g1, 256, 0, stream>>>(x, w_ih0, Xw, t0, Tc);
    rec_step<<<NBLK, 256, 0, stream>>>(w_ih0, w_hh0, w_ih1, w_hh1,
                                       b_ih0, b_hh0, b_ih1, b_hh1,
                                       embed_w, embed_b, proj_w, proj_b,
                                       Xw, out, h0_pub, h1_pub, flags,
                                       t0, Tc, (t0 + Tc) >= T_FULL ? 1 : 0);
  }
}